// Round 1
// baseline (1048.227 us; speedup 1.0000x reference)
//
#include <hip/hip_runtime.h>
#include <math.h>

typedef float2 c32;

__device__ __forceinline__ c32 cmulc(c32 a, c32 b){
    return make_float2(fmaf(a.x, b.x, -(a.y*b.y)), fmaf(a.x, b.y, a.y*b.x));
}
__device__ __forceinline__ c32 caddc(c32 a, c32 b){ return make_float2(a.x+b.x, a.y+b.y); }
__device__ __forceinline__ c32 csubc(c32 a, c32 b){ return make_float2(a.x-b.x, a.y-b.y); }

// In-register DIT FFT of size N (8 or 16), natural-order in/out.
// tw[m] = e^{sign*2*pi*i*m/16}  (sign baked into the table the caller built).
template<int N>
__device__ __forceinline__ void fftN(c32* a, const c32* tw){
    constexpr int LOG = (N == 16) ? 4 : 3;
    c32 b[N];
    #pragma unroll
    for (int i = 0; i < N; ++i){
        int r = 0;
        #pragma unroll
        for (int bb = 0; bb < LOG; ++bb) r = (r << 1) | ((i >> bb) & 1);
        b[i] = a[r];
    }
    #pragma unroll
    for (int len = 2; len <= N; len <<= 1){
        #pragma unroll
        for (int i = 0; i < N; i += len){
            #pragma unroll
            for (int j = 0; j < len/2; ++j){
                c32 t = b[i + j + len/2];
                if (j) t = cmulc(tw[j * (16/len)], t);
                c32 u = b[i + j];
                b[i + j]         = caddc(u, t);
                b[i + j + len/2] = csubc(u, t);
            }
        }
    }
    #pragma unroll
    for (int i = 0; i < N; ++i) a[i] = b[i];
}

// ---------------------------------------------------------------------------
// 1) conv3x3 stride2 SAME + gelu + partial spatial sums (deterministic)
//    grid: (B*T)*8 blocks, 256 thr. Block = 8 output rows of one frame.
//    part[(bt*8+rg)*32 + c] = sum over 512 positions of gelu(conv)
// ---------------------------------------------------------------------------
__global__ __launch_bounds__(256) void k_conv(const float* __restrict__ in,
                                              const float* __restrict__ cw,
                                              const float* __restrict__ cb,
                                              float* __restrict__ part)
{
    __shared__ float wl[864];
    __shared__ float red[4][32];
    const int tid = threadIdx.x;
    const int bt = blockIdx.x >> 3, rg = blockIdx.x & 7;
    for (int i = tid; i < 864; i += 256) wl[i] = cw[i];
    __syncthreads();
    const float* src = in + (size_t)bt * 49152;

    float acc[32];
    #pragma unroll
    for (int c = 0; c < 32; ++c) acc[c] = 0.f;

    for (int p = 0; p < 2; ++p){
        int pos = tid + p * 256;            // 0..511
        int oy = rg * 8 + (pos >> 6), ox = pos & 63;
        float iv[27];
        #pragma unroll
        for (int ky = 0; ky < 3; ++ky){
            int iy = 2*oy + ky;
            #pragma unroll
            for (int kx = 0; kx < 3; ++kx){
                int ix = 2*ox + kx;
                bool ok = (iy < 128) && (ix < 128);
                #pragma unroll
                for (int ci = 0; ci < 3; ++ci)
                    iv[(ky*3+kx)*3+ci] = ok ? src[((iy << 7) + ix) * 3 + ci] : 0.0f;
            }
        }
        #pragma unroll
        for (int c = 0; c < 32; ++c){
            float s = cb[c];
            #pragma unroll
            for (int q = 0; q < 27; ++q) s = fmaf(iv[q], wl[q*32 + c], s);
            float th = tanhf(0.7978845608028654f * fmaf(0.044715f * s, s * s, s));
            acc[c] += 0.5f * s * (1.0f + th);
        }
    }
    // wave (64-lane) reduce, then cross-wave via LDS (fixed order -> deterministic)
    #pragma unroll
    for (int c = 0; c < 32; ++c){
        float v = acc[c];
        #pragma unroll
        for (int off = 32; off; off >>= 1) v += __shfl_down(v, off, 64);
        acc[c] = v;
    }
    int wave = tid >> 6, lane = tid & 63;
    if (lane == 0){
        #pragma unroll
        for (int c = 0; c < 32; ++c) red[wave][c] = acc[c];
    }
    __syncthreads();
    if (tid < 32)
        part[blockIdx.x * 32 + tid] = red[0][tid] + red[1][tid] + red[2][tid] + red[3][tid];
}

// ---------------------------------------------------------------------------
// 2) gates: ctx mean -> alpha/delta (sigmoid), mu/gamma (softplus). 384 thr.
// ---------------------------------------------------------------------------
__global__ __launch_bounds__(64) void k_gates(const float* __restrict__ part,
    const float* __restrict__ wA, const float* __restrict__ bA,
    const float* __restrict__ wD, const float* __restrict__ bD,
    const float* __restrict__ wM, const float* __restrict__ bM,
    const float* __restrict__ wG, const float* __restrict__ bG,
    float* __restrict__ gA, float* __restrict__ gD,
    float* __restrict__ gM, float* __restrict__ gG)
{
    int g = blockIdx.x * 64 + threadIdx.x;
    if (g >= 384) return;
    int bt = g / 3, c = g % 3;
    float sA = bA[c], sD = bD[c], sM = bM[c], sG = bG[c];
    for (int j = 0; j < 32; ++j){
        float cs = 0.f;
        #pragma unroll
        for (int q = 0; q < 8; ++q) cs += part[(bt*8 + q)*32 + j];
        cs *= (1.0f / 4096.0f);
        sA = fmaf(cs, wA[j*3+c], sA);
        sD = fmaf(cs, wD[j*3+c], sD);
        sM = fmaf(cs, wM[j*3+c], sM);
        sG = fmaf(cs, wG[j*3+c], sG);
    }
    gA[g] = 1.0f / (1.0f + expf(-sA));
    gD[g] = 1.0f / (1.0f + expf(-sD));
    gM[g] = fmaxf(sM, 0.f) + log1pf(expf(-fabsf(sM)));
    gG[g] = fmaxf(sG, 0.f) + log1pf(expf(-fabsf(sG)));
}

// ---------------------------------------------------------------------------
// 3) spectral kernels: KE/KI[c][u][v] = rfft2(pad(k, 56)) via direct 256-tap DFT
// ---------------------------------------------------------------------------
__global__ __launch_bounds__(256) void k_spectral(const float* __restrict__ k_exc,
                                                  const float* __restrict__ k_inh,
                                                  float* __restrict__ KEw,
                                                  float* __restrict__ KIw)
{
    __shared__ c32 Wt[128];
    int tid = threadIdx.x;
    if (tid < 128){
        float ang = -0.049087385212340517f * (float)tid;   // -2*pi*t/128
        float s, co; sincosf(ang, &s, &co);
        Wt[tid] = make_float2(co, s);
    }
    __syncthreads();
    int g = blockIdx.x * 256 + tid;
    if (g >= 2 * 24960) return;
    int which = g / 24960, r = g % 24960;
    int c = r / 8320, uv = r % 8320;
    int u_ = uv / 65, v_ = uv % 65;
    const float* kk = which ? k_inh : k_exc;
    float ar = 0.f, ai = 0.f;
    for (int y = 0; y < 16; ++y){
        int pu = u_ * (56 + y);
        #pragma unroll
        for (int x = 0; x < 16; ++x){
            int idx = (pu + v_ * (56 + x)) & 127;
            float kv = kk[(y*16 + x)*3 + c];
            c32 w = Wt[idx];
            ar = fmaf(kv, w.x, ar);
            ai = fmaf(kv, w.y, ai);
        }
    }
    ((float2*)(which ? KIw : KEw))[c*8320 + uv] = make_float2(ar, ai);
}

// ---------------------------------------------------------------------------
// 4) forward rfft2 per (b,t,c) image.  4-step FFT-128 = FFT8 x FFT16.
//    Row pass packs rows (2r, 2r+1) into one complex FFT.  Output
//    U_ws[bt][c][u][v] (v=0..64), complex interleaved.
// ---------------------------------------------------------------------------
__global__ __launch_bounds__(512) void k_fft_fwd(const float* __restrict__ in,
                                                 float* __restrict__ U_ws)
{
    __shared__ c32 A[8320];     // [64][130] for rows, flat [128][65] after unpack
    __shared__ c32 Bf[8320];    // [64][130] for Z rows, flat [128][65] for col out
    __shared__ c32 Wt[128];
    const int tid = threadIdx.x;
    const int img = blockIdx.x;             // bt*3 + c
    const int bt = img / 3, c = img % 3;

    if (tid < 128){
        float ang = -0.049087385212340517f * (float)tid;
        float s, co; sincosf(ang, &s, &co);
        Wt[tid] = make_float2(co, s);
    }
    __syncthreads();
    c32 tw8[8];
    #pragma unroll
    for (int m = 0; m < 8; ++m) tw8[m] = Wt[8*m];

    // pack: A[r*130+x] = in[2r][x] + i*in[2r+1][x]
    const float* src = in + (size_t)bt * 49152 + c;
    for (int p = tid; p < 64*128; p += blockDim.x){
        int r = p >> 7, x = p & 127;
        float re = src[(size_t)((2*r)   * 128 + x) * 3];
        float im = src[(size_t)((2*r+1) * 128 + x) * 3];
        A[r*130 + x] = make_float2(re, im);
    }
    __syncthreads();

    // row stage1: FFT8 over n2 (stride 16), twiddle W[n1*k2], in place
    for (int task = tid; task < 64*16; task += blockDim.x){
        int r = task >> 4, n1 = task & 15;
        c32 v[8];
        #pragma unroll
        for (int n2 = 0; n2 < 8; ++n2) v[n2] = A[r*130 + n1 + 16*n2];
        fftN<8>(v, tw8);
        #pragma unroll
        for (int k2 = 0; k2 < 8; ++k2)
            A[r*130 + n1 + 16*k2] = (k2 == 0) ? v[0] : cmulc(Wt[n1*k2], v[k2]);
    }
    __syncthreads();
    // row stage2: FFT16 over n1 (contiguous), Z[r][k2+8k1] -> Bf
    for (int task = tid; task < 64*8; task += blockDim.x){
        int r = task >> 3, k2 = task & 7;
        c32 v[16];
        #pragma unroll
        for (int n1 = 0; n1 < 16; ++n1) v[n1] = A[r*130 + 16*k2 + n1];
        fftN<16>(v, tw8);
        #pragma unroll
        for (int k1 = 0; k1 < 16; ++k1) Bf[r*130 + k2 + 8*k1] = v[k1];
    }
    __syncthreads();
    // unpack the two packed real rows: A_flat[y*65+v], y = 2r / 2r+1
    for (int task = tid; task < 64*65; task += blockDim.x){
        int r = task / 65, v_ = task % 65;
        c32 zk = Bf[r*130 + v_];
        c32 zn = Bf[r*130 + ((128 - v_) & 127)];
        A[(2*r)  *65 + v_] = make_float2(0.5f*(zk.x + zn.x),  0.5f*(zk.y - zn.y));
        A[(2*r+1)*65 + v_] = make_float2(0.5f*(zk.y + zn.y), -0.5f*(zk.x - zn.x));
    }
    __syncthreads();
    // col stage1: FFT8 over n2 (row stride 16), per column v, in place
    for (int task = tid; task < 16*65; task += blockDim.x){
        int n1 = task / 65, v_ = task % 65;
        c32 v[8];
        #pragma unroll
        for (int n2 = 0; n2 < 8; ++n2) v[n2] = A[(n1 + 16*n2)*65 + v_];
        fftN<8>(v, tw8);
        #pragma unroll
        for (int k2 = 0; k2 < 8; ++k2)
            A[(n1 + 16*k2)*65 + v_] = (k2 == 0) ? v[0] : cmulc(Wt[n1*k2], v[k2]);
    }
    __syncthreads();
    // col stage2: FFT16 over n1, final U[u][v] -> Bf flat
    for (int task = tid; task < 8*65; task += blockDim.x){
        int k2 = task / 65, v_ = task % 65;
        c32 v[16];
        #pragma unroll
        for (int n1 = 0; n1 < 16; ++n1) v[n1] = A[(16*k2 + n1)*65 + v_];
        fftN<16>(v, tw8);
        #pragma unroll
        for (int k1 = 0; k1 < 16; ++k1) Bf[(k2 + 8*k1)*65 + v_] = v[k1];
    }
    __syncthreads();
    float2* dst = ((float2*)U_ws) + (size_t)img * 8320;
    for (int p = tid; p < 8320; p += blockDim.x) dst[p] = Bf[p];
}

// ---------------------------------------------------------------------------
// 5) sequential T-scan (in place over U):  x' = 0.9a*x + (-KI*mu)*y + U,
//    y' = (KE*ga)*x + 0.9d*y ; store y' over U.
// ---------------------------------------------------------------------------
__global__ __launch_bounds__(256) void k_scan(float* __restrict__ U,
    const float* __restrict__ KEw, const float* __restrict__ KIw,
    const float* __restrict__ gA, const float* __restrict__ gD,
    const float* __restrict__ gM, const float* __restrict__ gG)
{
    int g = blockIdx.x * 256 + threadIdx.x;
    if (g >= 4*3*128*65) return;
    int b = g / 24960, r = g % 24960;
    int c = r / 8320, uv = r % 8320;
    float2 ke = ((const float2*)KEw)[c*8320 + uv];
    float2 ki = ((const float2*)KIw)[c*8320 + uv];
    float2* Up = (float2*)U;
    float xr = 0.f, xi = 0.f, yr = 0.f, yi = 0.f;
    for (int t = 0; t < 32; ++t){
        int btc = (b*32 + t)*3 + c;
        float al = 0.9f * gA[btc], de = 0.9f * gD[btc];
        float mu = gM[btc],       ga = gG[btc];
        float axr = -ki.x * mu, axi = -ki.y * mu;
        float ayr =  ke.x * ga, ayi =  ke.y * ga;
        size_t iu = (size_t)btc * 8320 + uv;
        float2 uin = Up[iu];
        float nxr = fmaf(al, xr, fmaf(axr, yr, fmaf(-axi, yi, uin.x)));
        float nxi = fmaf(al, xi, fmaf(axr, yi, fmaf( axi, yr, uin.y)));
        float nyr = fmaf(ayr, xr, fmaf(-ayi, xi, de * yr));
        float nyi = fmaf(ayr, xi, fmaf( ayi, xr, de * yi));
        Up[iu] = make_float2(nyr, nyi);
        xr = nxr; xi = nxi; yr = nyr; yi = nyi;
    }
}

// ---------------------------------------------------------------------------
// 6) inverse: per (b,t,c): column IFFT-128 (65 cols), then real irfft-128 per
//    row via half-size complex IFFT-64 (drops imag of bins 0/64 like numpy).
//    Final scale 1/8192 folds 1/128(col) * 1/64(half-size row).
// ---------------------------------------------------------------------------
__global__ __launch_bounds__(512) void k_fft_inv(const float* __restrict__ Y_ws,
                                                 float* __restrict__ out)
{
    __shared__ c32 A[8320];
    __shared__ c32 Bf[8320];
    __shared__ c32 Wt[128];                 // e^{+2 pi i t/128}
    const int tid = threadIdx.x;
    const int img = blockIdx.x;
    const int bt = img / 3, c = img % 3;

    if (tid < 128){
        float ang = 0.049087385212340517f * (float)tid;
        float s, co; sincosf(ang, &s, &co);
        Wt[tid] = make_float2(co, s);
    }
    __syncthreads();
    c32 tw8[8];
    #pragma unroll
    for (int m = 0; m < 8; ++m) tw8[m] = Wt[8*m];

    const float2* srcv = ((const float2*)Y_ws) + (size_t)img * 8320;
    for (int p = tid; p < 8320; p += blockDim.x) A[p] = srcv[p];
    __syncthreads();

    // col IFFT stage1 (in place, per column v)
    for (int task = tid; task < 16*65; task += blockDim.x){
        int n1 = task / 65, v_ = task % 65;
        c32 v[8];
        #pragma unroll
        for (int n2 = 0; n2 < 8; ++n2) v[n2] = A[(n1 + 16*n2)*65 + v_];
        fftN<8>(v, tw8);
        #pragma unroll
        for (int k2 = 0; k2 < 8; ++k2)
            A[(n1 + 16*k2)*65 + v_] = (k2 == 0) ? v[0] : cmulc(Wt[n1*k2], v[k2]);
    }
    __syncthreads();
    // col IFFT stage2 -> Bf[h][v] = row spectra (unscaled)
    for (int task = tid; task < 8*65; task += blockDim.x){
        int k2 = task / 65, v_ = task % 65;
        c32 v[16];
        #pragma unroll
        for (int n1 = 0; n1 < 16; ++n1) v[n1] = A[(16*k2 + n1)*65 + v_];
        fftN<16>(v, tw8);
        #pragma unroll
        for (int k1 = 0; k1 < 16; ++k1) Bf[(k2 + 8*k1)*65 + v_] = v[k1];
    }
    __syncthreads();
    // E/O prep per row: Z[k] = E[k] + i*O[k], k=0..63 -> A[y*65+k]
    for (int task = tid; task < 128*64; task += blockDim.x){
        int y = task >> 6, k = task & 63;
        c32 Xk = Bf[y*65 + k];
        c32 Xn = Bf[y*65 + 64 - k];
        if (k == 0){ Xk.y = 0.f; Xn.y = 0.f; }     // numpy drops imag of bins 0,64
        float Er = 0.5f*(Xk.x + Xn.x), Ei = 0.5f*(Xk.y - Xn.y);
        c32 d  = make_float2(0.5f*(Xk.x - Xn.x), 0.5f*(Xk.y + Xn.y));
        c32 O  = cmulc(Wt[k], d);                  // e^{+2 pi i k/128} * d
        A[y*65 + k] = make_float2(Er - O.y, Ei + O.x);
    }
    __syncthreads();
    // row IFFT-64 stage1: FFT8 over b at slots a+8b, twiddle e^{+2pi i a c/64}
    for (int task = tid; task < 128*8; task += blockDim.x){
        int y = task >> 3, a = task & 7;
        c32 v[8];
        #pragma unroll
        for (int b2 = 0; b2 < 8; ++b2) v[b2] = A[y*65 + a + 8*b2];
        fftN<8>(v, tw8);
        #pragma unroll
        for (int c2 = 0; c2 < 8; ++c2)
            A[y*65 + a + 8*c2] = (c2 == 0) ? v[0] : cmulc(Wt[2*a*c2], v[c2]);
    }
    __syncthreads();
    // row IFFT-64 stage2: FFT8 over a at slots 8c2+a -> Bf[y*65 + c2+8d]
    for (int task = tid; task < 128*8; task += blockDim.x){
        int y = task >> 3, c2 = task & 7;
        c32 v[8];
        #pragma unroll
        for (int a = 0; a < 8; ++a) v[a] = A[y*65 + 8*c2 + a];
        fftN<8>(v, tw8);
        #pragma unroll
        for (int d = 0; d < 8; ++d) Bf[y*65 + c2 + 8*d] = v[d];
    }
    __syncthreads();
    // emit: x[2m] = Re z, x[2m+1] = Im z, scale 1/8192
    float* dst = out + (size_t)bt * 49152 + c;
    const float sc = 1.0f / 8192.0f;
    for (int p = tid; p < 128*64; p += blockDim.x){
        int y = p >> 6, m = p & 63;
        c32 z = Bf[y*65 + m];
        dst[(size_t)((y << 7) + 2*m    ) * 3] = z.x * sc;
        dst[(size_t)((y << 7) + 2*m + 1) * 3] = z.y * sc;
    }
}

// ---------------------------------------------------------------------------
extern "C" void kernel_launch(void* const* d_in, const int* in_sizes, int n_in,
                              void* d_out, int out_size, void* d_ws, size_t ws_size,
                              hipStream_t stream)
{
    (void)in_sizes; (void)n_in; (void)out_size; (void)ws_size;
    const float* in   = (const float*)d_in[0];
    const float* cw   = (const float*)d_in[1];
    const float* cb   = (const float*)d_in[2];
    const float* wA   = (const float*)d_in[3];
    const float* bA   = (const float*)d_in[4];
    const float* wD   = (const float*)d_in[5];
    const float* bD   = (const float*)d_in[6];
    const float* wM   = (const float*)d_in[7];
    const float* bM   = (const float*)d_in[8];
    const float* wG   = (const float*)d_in[9];
    const float* bG   = (const float*)d_in[10];
    const float* kex  = (const float*)d_in[11];
    const float* kin  = (const float*)d_in[12];
    float* out = (float*)d_out;
    float* ws  = (float*)d_ws;

    float* part = ws;                    // 1024*32            = 32768
    float* gA   = ws + 32768;            // 384
    float* gD   = gA + 384;
    float* gM   = gD + 384;
    float* gG   = gM + 384;              // ends 34304
    float* KEw  = ws + 34304;            // 3*128*65*2         = 49920
    float* KIw  = KEw + 49920;           // ends 134144
    float* U    = ws + 134144;           // 128*3*128*65*2     = 6389760 (in-place scan)

    k_conv    <<<dim3(1024), dim3(256), 0, stream>>>(in, cw, cb, part);
    k_gates   <<<dim3(6),    dim3(64),  0, stream>>>(part, wA, bA, wD, bD, wM, bM, wG, bG,
                                                     gA, gD, gM, gG);
    k_spectral<<<dim3(195),  dim3(256), 0, stream>>>(kex, kin, KEw, KIw);
    k_fft_fwd <<<dim3(384),  dim3(512), 0, stream>>>(in, U);
    k_scan    <<<dim3(390),  dim3(256), 0, stream>>>(U, KEw, KIw, gA, gD, gM, gG);
    k_fft_inv <<<dim3(384),  dim3(512), 0, stream>>>(U, out);
}

// Round 2
// 232.781 us; speedup vs baseline: 4.5031x; 4.5031x over previous
//
#include <hip/hip_runtime.h>
#include <math.h>

typedef float2 c32;

__device__ __forceinline__ c32 cmulc(c32 a, c32 b){
    return make_float2(fmaf(a.x, b.x, -(a.y*b.y)), fmaf(a.x, b.y, a.y*b.x));
}
__device__ __forceinline__ c32 caddc(c32 a, c32 b){ return make_float2(a.x+b.x, a.y+b.y); }
__device__ __forceinline__ c32 csubc(c32 a, c32 b){ return make_float2(a.x-b.x, a.y-b.y); }

// In-register DIT FFT of size N (8 or 16), natural-order in/out.
// tw[m] = e^{sign*2*pi*i*m/16}  (sign baked into the table the caller built).
template<int N>
__device__ __forceinline__ void fftN(c32* a, const c32* tw){
    constexpr int LOG = (N == 16) ? 4 : 3;
    c32 b[N];
    #pragma unroll
    for (int i = 0; i < N; ++i){
        int r = 0;
        #pragma unroll
        for (int bb = 0; bb < LOG; ++bb) r = (r << 1) | ((i >> bb) & 1);
        b[i] = a[r];
    }
    #pragma unroll
    for (int len = 2; len <= N; len <<= 1){
        #pragma unroll
        for (int i = 0; i < N; i += len){
            #pragma unroll
            for (int j = 0; j < len/2; ++j){
                c32 t = b[i + j + len/2];
                if (j) t = cmulc(tw[j * (16/len)], t);
                c32 u = b[i + j];
                b[i + j]         = caddc(u, t);
                b[i + j + len/2] = csubc(u, t);
            }
        }
    }
    #pragma unroll
    for (int i = 0; i < N; ++i) a[i] = b[i];
}

// ---------------------------------------------------------------------------
// 1) conv3x3 stride2 SAME + gelu + partial spatial sums (deterministic)
//    grid: (B*T)*8 blocks, 256 thr. Block = 8 output rows of one frame.
//    LDS-staged input (parity planes), channel groups of 8 -> no spills.
//    part[(bt*8+rg)*32 + c] = sum over 512 positions of gelu(conv)
// ---------------------------------------------------------------------------
__global__ __launch_bounds__(256) void k_conv(const float* __restrict__ in,
                                              const float* __restrict__ cw,
                                              const float* __restrict__ cb,
                                              float* __restrict__ part)
{
    // xs[c][parity][row][xhalf] : x = 2*xhalf + parity, rows 0..16 of the slab
    __shared__ float xs[3][2][17][68];
    __shared__ float wl[864];
    __shared__ float cbl[32];
    __shared__ float red[4][32];
    const int tid = threadIdx.x;
    const int bt = blockIdx.x >> 3, rg = blockIdx.x & 7;

    for (int i = tid; i < 864; i += 256) wl[i] = cw[i];
    if (tid < 32) cbl[tid] = cb[tid];
    // zero even-plane column 64 (x == 128 boundary pad)
    if (tid < 51){ int r = tid / 3, c = tid % 3; xs[c][0][r][64] = 0.0f; }

    // stage slab: input rows r0..r0+16 (17 rows * 384 floats), coalesced
    const int r0 = 16 * rg;
    const float* src = in + (size_t)bt * 49152 + (size_t)r0 * 384;
    for (int i = tid; i < 17 * 384; i += 256){
        int r = i / 384, q = i % 384;
        int x = q / 3, c = q - 3 * x;
        float v = (r0 + r < 128) ? src[i] : 0.0f;
        xs[c][x & 1][r][x >> 1] = v;
    }
    __syncthreads();

    const int wave = tid >> 6, lane = tid & 63;

    #pragma unroll
    for (int g = 0; g < 4; ++g){
        float acc8[8];
        #pragma unroll
        for (int cc = 0; cc < 8; ++cc) acc8[cc] = 0.0f;

        #pragma unroll
        for (int p = 0; p < 2; ++p){
            int pos = p * 256 + tid;            // 0..511
            int oyl = pos >> 6, ox = pos & 63;
            float iv[27];
            #pragma unroll
            for (int ky = 0; ky < 3; ++ky){
                int row = 2 * oyl + ky;
                #pragma unroll
                for (int ci = 0; ci < 3; ++ci){
                    iv[(ky*3 + 0)*3 + ci] = xs[ci][0][row][ox];      // x = 2ox
                    iv[(ky*3 + 1)*3 + ci] = xs[ci][1][row][ox];      // x = 2ox+1
                    iv[(ky*3 + 2)*3 + ci] = xs[ci][0][row][ox + 1];  // x = 2ox+2
                }
            }
            #pragma unroll
            for (int cc = 0; cc < 8; ++cc){
                int c = g * 8 + cc;
                float s = cbl[c];
                #pragma unroll
                for (int q = 0; q < 27; ++q) s = fmaf(iv[q], wl[q*32 + c], s);
                float th = tanhf(0.7978845608028654f * fmaf(0.044715f * s, s * s, s));
                acc8[cc] += 0.5f * s * (1.0f + th);
            }
        }
        #pragma unroll
        for (int cc = 0; cc < 8; ++cc){
            float v = acc8[cc];
            #pragma unroll
            for (int off = 32; off; off >>= 1) v += __shfl_down(v, off, 64);
            if (lane == 0) red[wave][g*8 + cc] = v;
        }
    }
    __syncthreads();
    if (tid < 32)
        part[blockIdx.x * 32 + tid] = red[0][tid] + red[1][tid] + red[2][tid] + red[3][tid];
}

// ---------------------------------------------------------------------------
// 2) gates: ctx mean -> alpha/delta (sigmoid), mu/gamma (softplus). 384 thr.
// ---------------------------------------------------------------------------
__global__ __launch_bounds__(64) void k_gates(const float* __restrict__ part,
    const float* __restrict__ wA, const float* __restrict__ bA,
    const float* __restrict__ wD, const float* __restrict__ bD,
    const float* __restrict__ wM, const float* __restrict__ bM,
    const float* __restrict__ wG, const float* __restrict__ bG,
    float* __restrict__ gA, float* __restrict__ gD,
    float* __restrict__ gM, float* __restrict__ gG)
{
    int g = blockIdx.x * 64 + threadIdx.x;
    if (g >= 384) return;
    int bt = g / 3, c = g % 3;
    float sA = bA[c], sD = bD[c], sM = bM[c], sG = bG[c];
    for (int j = 0; j < 32; ++j){
        float cs = 0.f;
        #pragma unroll
        for (int q = 0; q < 8; ++q) cs += part[(bt*8 + q)*32 + j];
        cs *= (1.0f / 4096.0f);
        sA = fmaf(cs, wA[j*3+c], sA);
        sD = fmaf(cs, wD[j*3+c], sD);
        sM = fmaf(cs, wM[j*3+c], sM);
        sG = fmaf(cs, wG[j*3+c], sG);
    }
    gA[g] = 1.0f / (1.0f + expf(-sA));
    gD[g] = 1.0f / (1.0f + expf(-sD));
    gM[g] = fmaxf(sM, 0.f) + log1pf(expf(-fabsf(sM)));
    gG[g] = fmaxf(sG, 0.f) + log1pf(expf(-fabsf(sG)));
}

// ---------------------------------------------------------------------------
// 3) spectral kernels: KE/KI[c][u][v] = rfft2(pad(k, 56)) via direct 256-tap DFT
// ---------------------------------------------------------------------------
__global__ __launch_bounds__(256) void k_spectral(const float* __restrict__ k_exc,
                                                  const float* __restrict__ k_inh,
                                                  float* __restrict__ KEw,
                                                  float* __restrict__ KIw)
{
    __shared__ c32 Wt[128];
    int tid = threadIdx.x;
    if (tid < 128){
        float ang = -0.049087385212340517f * (float)tid;   // -2*pi*t/128
        float s, co; sincosf(ang, &s, &co);
        Wt[tid] = make_float2(co, s);
    }
    __syncthreads();
    int g = blockIdx.x * 256 + tid;
    if (g >= 2 * 24960) return;
    int which = g / 24960, r = g % 24960;
    int c = r / 8320, uv = r % 8320;
    int u_ = uv / 65, v_ = uv % 65;
    const float* kk = which ? k_inh : k_exc;
    float ar = 0.f, ai = 0.f;
    for (int y = 0; y < 16; ++y){
        int pu = u_ * (56 + y);
        #pragma unroll
        for (int x = 0; x < 16; ++x){
            int idx = (pu + v_ * (56 + x)) & 127;
            float kv = kk[(y*16 + x)*3 + c];
            c32 w = Wt[idx];
            ar = fmaf(kv, w.x, ar);
            ai = fmaf(kv, w.y, ai);
        }
    }
    ((float2*)(which ? KIw : KEw))[c*8320 + uv] = make_float2(ar, ai);
}

// ---------------------------------------------------------------------------
// 4) forward rfft2 per (b,t,c) image.  4-step FFT-128 = FFT8 x FFT16.
//    Row pass packs rows (2r, 2r+1) into one complex FFT.  Output
//    U_ws[bt][c][u][v] (v=0..64), complex interleaved.
// ---------------------------------------------------------------------------
__global__ __launch_bounds__(512) void k_fft_fwd(const float* __restrict__ in,
                                                 float* __restrict__ U_ws)
{
    __shared__ c32 A[8320];     // [64][130] for rows, flat [128][65] after unpack
    __shared__ c32 Bf[8320];    // [64][130] for Z rows, flat [128][65] for col out
    __shared__ c32 Wt[128];
    const int tid = threadIdx.x;
    const int img = blockIdx.x;             // bt*3 + c
    const int bt = img / 3, c = img % 3;

    if (tid < 128){
        float ang = -0.049087385212340517f * (float)tid;
        float s, co; sincosf(ang, &s, &co);
        Wt[tid] = make_float2(co, s);
    }
    __syncthreads();
    c32 tw8[8];
    #pragma unroll
    for (int m = 0; m < 8; ++m) tw8[m] = Wt[8*m];

    // pack: A[r*130+x] = in[2r][x] + i*in[2r+1][x]
    const float* src = in + (size_t)bt * 49152 + c;
    for (int p = tid; p < 64*128; p += blockDim.x){
        int r = p >> 7, x = p & 127;
        float re = src[(size_t)((2*r)   * 128 + x) * 3];
        float im = src[(size_t)((2*r+1) * 128 + x) * 3];
        A[r*130 + x] = make_float2(re, im);
    }
    __syncthreads();

    // row stage1: FFT8 over n2 (stride 16), twiddle W[n1*k2], in place
    for (int task = tid; task < 64*16; task += blockDim.x){
        int r = task >> 4, n1 = task & 15;
        c32 v[8];
        #pragma unroll
        for (int n2 = 0; n2 < 8; ++n2) v[n2] = A[r*130 + n1 + 16*n2];
        fftN<8>(v, tw8);
        #pragma unroll
        for (int k2 = 0; k2 < 8; ++k2)
            A[r*130 + n1 + 16*k2] = (k2 == 0) ? v[0] : cmulc(Wt[n1*k2], v[k2]);
    }
    __syncthreads();
    // row stage2: FFT16 over n1 (contiguous), Z[r][k2+8k1] -> Bf
    for (int task = tid; task < 64*8; task += blockDim.x){
        int r = task >> 3, k2 = task & 7;
        c32 v[16];
        #pragma unroll
        for (int n1 = 0; n1 < 16; ++n1) v[n1] = A[r*130 + 16*k2 + n1];
        fftN<16>(v, tw8);
        #pragma unroll
        for (int k1 = 0; k1 < 16; ++k1) Bf[r*130 + k2 + 8*k1] = v[k1];
    }
    __syncthreads();
    // unpack the two packed real rows: A_flat[y*65+v], y = 2r / 2r+1
    for (int task = tid; task < 64*65; task += blockDim.x){
        int r = task / 65, v_ = task % 65;
        c32 zk = Bf[r*130 + v_];
        c32 zn = Bf[r*130 + ((128 - v_) & 127)];
        A[(2*r)  *65 + v_] = make_float2(0.5f*(zk.x + zn.x),  0.5f*(zk.y - zn.y));
        A[(2*r+1)*65 + v_] = make_float2(0.5f*(zk.y + zn.y), -0.5f*(zk.x - zn.x));
    }
    __syncthreads();
    // col stage1: FFT8 over n2 (row stride 16), per column v, in place
    for (int task = tid; task < 16*65; task += blockDim.x){
        int n1 = task / 65, v_ = task % 65;
        c32 v[8];
        #pragma unroll
        for (int n2 = 0; n2 < 8; ++n2) v[n2] = A[(n1 + 16*n2)*65 + v_];
        fftN<8>(v, tw8);
        #pragma unroll
        for (int k2 = 0; k2 < 8; ++k2)
            A[(n1 + 16*k2)*65 + v_] = (k2 == 0) ? v[0] : cmulc(Wt[n1*k2], v[k2]);
    }
    __syncthreads();
    // col stage2: FFT16 over n1, final U[u][v] -> Bf flat
    for (int task = tid; task < 8*65; task += blockDim.x){
        int k2 = task / 65, v_ = task % 65;
        c32 v[16];
        #pragma unroll
        for (int n1 = 0; n1 < 16; ++n1) v[n1] = A[(16*k2 + n1)*65 + v_];
        fftN<16>(v, tw8);
        #pragma unroll
        for (int k1 = 0; k1 < 16; ++k1) Bf[(k2 + 8*k1)*65 + v_] = v[k1];
    }
    __syncthreads();
    float2* dst = ((float2*)U_ws) + (size_t)img * 8320;
    for (int p = tid; p < 8320; p += blockDim.x) dst[p] = Bf[p];
}

// ---------------------------------------------------------------------------
// 5) sequential T-scan (in place over U):  x' = 0.9a*x + (-KI*mu)*y + U,
//    y' = (KE*ga)*x + 0.9d*y ; store y' over U.
// ---------------------------------------------------------------------------
__global__ __launch_bounds__(256) void k_scan(float* __restrict__ U,
    const float* __restrict__ KEw, const float* __restrict__ KIw,
    const float* __restrict__ gA, const float* __restrict__ gD,
    const float* __restrict__ gM, const float* __restrict__ gG)
{
    int g = blockIdx.x * 256 + threadIdx.x;
    if (g >= 4*3*128*65) return;
    int b = g / 24960, r = g % 24960;
    int c = r / 8320, uv = r % 8320;
    float2 ke = ((const float2*)KEw)[c*8320 + uv];
    float2 ki = ((const float2*)KIw)[c*8320 + uv];
    float2* Up = (float2*)U;
    float xr = 0.f, xi = 0.f, yr = 0.f, yi = 0.f;
    for (int t = 0; t < 32; ++t){
        int btc = (b*32 + t)*3 + c;
        float al = 0.9f * gA[btc], de = 0.9f * gD[btc];
        float mu = gM[btc],       ga = gG[btc];
        float axr = -ki.x * mu, axi = -ki.y * mu;
        float ayr =  ke.x * ga, ayi =  ke.y * ga;
        size_t iu = (size_t)btc * 8320 + uv;
        float2 uin = Up[iu];
        float nxr = fmaf(al, xr, fmaf(axr, yr, fmaf(-axi, yi, uin.x)));
        float nxi = fmaf(al, xi, fmaf(axr, yi, fmaf( axi, yr, uin.y)));
        float nyr = fmaf(ayr, xr, fmaf(-ayi, xi, de * yr));
        float nyi = fmaf(ayr, xi, fmaf( ayi, xr, de * yi));
        Up[iu] = make_float2(nyr, nyi);
        xr = nxr; xi = nxi; yr = nyr; yi = nyi;
    }
}

// ---------------------------------------------------------------------------
// 6) inverse: per (b,t,c): column IFFT-128 (65 cols), then real irfft-128 per
//    row via half-size complex IFFT-64 (drops imag of bins 0/64 like numpy).
//    Final scale 1/8192 folds 1/128(col) * 1/64(half-size row).
// ---------------------------------------------------------------------------
__global__ __launch_bounds__(512) void k_fft_inv(const float* __restrict__ Y_ws,
                                                 float* __restrict__ out)
{
    __shared__ c32 A[8320];
    __shared__ c32 Bf[8320];
    __shared__ c32 Wt[128];                 // e^{+2 pi i t/128}
    const int tid = threadIdx.x;
    const int img = blockIdx.x;
    const int bt = img / 3, c = img % 3;

    if (tid < 128){
        float ang = 0.049087385212340517f * (float)tid;
        float s, co; sincosf(ang, &s, &co);
        Wt[tid] = make_float2(co, s);
    }
    __syncthreads();
    c32 tw8[8];
    #pragma unroll
    for (int m = 0; m < 8; ++m) tw8[m] = Wt[8*m];

    const float2* srcv = ((const float2*)Y_ws) + (size_t)img * 8320;
    for (int p = tid; p < 8320; p += blockDim.x) A[p] = srcv[p];
    __syncthreads();

    // col IFFT stage1 (in place, per column v)
    for (int task = tid; task < 16*65; task += blockDim.x){
        int n1 = task / 65, v_ = task % 65;
        c32 v[8];
        #pragma unroll
        for (int n2 = 0; n2 < 8; ++n2) v[n2] = A[(n1 + 16*n2)*65 + v_];
        fftN<8>(v, tw8);
        #pragma unroll
        for (int k2 = 0; k2 < 8; ++k2)
            A[(n1 + 16*k2)*65 + v_] = (k2 == 0) ? v[0] : cmulc(Wt[n1*k2], v[k2]);
    }
    __syncthreads();
    // col IFFT stage2 -> Bf[h][v] = row spectra (unscaled)
    for (int task = tid; task < 8*65; task += blockDim.x){
        int k2 = task / 65, v_ = task % 65;
        c32 v[16];
        #pragma unroll
        for (int n1 = 0; n1 < 16; ++n1) v[n1] = A[(16*k2 + n1)*65 + v_];
        fftN<16>(v, tw8);
        #pragma unroll
        for (int k1 = 0; k1 < 16; ++k1) Bf[(k2 + 8*k1)*65 + v_] = v[k1];
    }
    __syncthreads();
    // E/O prep per row: Z[k] = E[k] + i*O[k], k=0..63 -> A[y*65+k]
    for (int task = tid; task < 128*64; task += blockDim.x){
        int y = task >> 6, k = task & 63;
        c32 Xk = Bf[y*65 + k];
        c32 Xn = Bf[y*65 + 64 - k];
        if (k == 0){ Xk.y = 0.f; Xn.y = 0.f; }     // numpy drops imag of bins 0,64
        float Er = 0.5f*(Xk.x + Xn.x), Ei = 0.5f*(Xk.y - Xn.y);
        c32 d  = make_float2(0.5f*(Xk.x - Xn.x), 0.5f*(Xk.y + Xn.y));
        c32 O  = cmulc(Wt[k], d);                  // e^{+2 pi i k/128} * d
        A[y*65 + k] = make_float2(Er - O.y, Ei + O.x);
    }
    __syncthreads();
    // row IFFT-64 stage1: FFT8 over b at slots a+8b, twiddle e^{+2pi i a c/64}
    for (int task = tid; task < 128*8; task += blockDim.x){
        int y = task >> 3, a = task & 7;
        c32 v[8];
        #pragma unroll
        for (int b2 = 0; b2 < 8; ++b2) v[b2] = A[y*65 + a + 8*b2];
        fftN<8>(v, tw8);
        #pragma unroll
        for (int c2 = 0; c2 < 8; ++c2)
            A[y*65 + a + 8*c2] = (c2 == 0) ? v[0] : cmulc(Wt[2*a*c2], v[c2]);
    }
    __syncthreads();
    // row IFFT-64 stage2: FFT8 over a at slots 8c2+a -> Bf[y*65 + c2+8d]
    for (int task = tid; task < 128*8; task += blockDim.x){
        int y = task >> 3, c2 = task & 7;
        c32 v[8];
        #pragma unroll
        for (int a = 0; a < 8; ++a) v[a] = A[y*65 + 8*c2 + a];
        fftN<8>(v, tw8);
        #pragma unroll
        for (int d = 0; d < 8; ++d) Bf[y*65 + c2 + 8*d] = v[d];
    }
    __syncthreads();
    // emit: x[2m] = Re z, x[2m+1] = Im z, scale 1/8192
    float* dst = out + (size_t)bt * 49152 + c;
    const float sc = 1.0f / 8192.0f;
    for (int p = tid; p < 128*64; p += blockDim.x){
        int y = p >> 6, m = p & 63;
        c32 z = Bf[y*65 + m];
        dst[(size_t)((y << 7) + 2*m    ) * 3] = z.x * sc;
        dst[(size_t)((y << 7) + 2*m + 1) * 3] = z.y * sc;
    }
}

// ---------------------------------------------------------------------------
extern "C" void kernel_launch(void* const* d_in, const int* in_sizes, int n_in,
                              void* d_out, int out_size, void* d_ws, size_t ws_size,
                              hipStream_t stream)
{
    (void)in_sizes; (void)n_in; (void)out_size; (void)ws_size;
    const float* in   = (const float*)d_in[0];
    const float* cw   = (const float*)d_in[1];
    const float* cb   = (const float*)d_in[2];
    const float* wA   = (const float*)d_in[3];
    const float* bA   = (const float*)d_in[4];
    const float* wD   = (const float*)d_in[5];
    const float* bD   = (const float*)d_in[6];
    const float* wM   = (const float*)d_in[7];
    const float* bM   = (const float*)d_in[8];
    const float* wG   = (const float*)d_in[9];
    const float* bG   = (const float*)d_in[10];
    const float* kex  = (const float*)d_in[11];
    const float* kin  = (const float*)d_in[12];
    float* out = (float*)d_out;
    float* ws  = (float*)d_ws;

    float* part = ws;                    // 1024*32            = 32768
    float* gA   = ws + 32768;            // 384
    float* gD   = gA + 384;
    float* gM   = gD + 384;
    float* gG   = gM + 384;              // ends 34304
    float* KEw  = ws + 34304;            // 3*128*65*2         = 49920
    float* KIw  = KEw + 49920;           // ends 134144
    float* U    = ws + 134144;           // 128*3*128*65*2     = 6389760 (in-place scan)

    k_conv    <<<dim3(1024), dim3(256), 0, stream>>>(in, cw, cb, part);
    k_gates   <<<dim3(6),    dim3(64),  0, stream>>>(part, wA, bA, wD, bD, wM, bM, wG, bG,
                                                     gA, gD, gM, gG);
    k_spectral<<<dim3(195),  dim3(256), 0, stream>>>(kex, kin, KEw, KIw);
    k_fft_fwd <<<dim3(384),  dim3(512), 0, stream>>>(in, U);
    k_scan    <<<dim3(390),  dim3(256), 0, stream>>>(U, KEw, KIw, gA, gD, gM, gG);
    k_fft_inv <<<dim3(384),  dim3(512), 0, stream>>>(U, out);
}

// Round 3
// 159.351 us; speedup vs baseline: 6.5781x; 1.4608x over previous
//
#include <hip/hip_runtime.h>
#include <math.h>

typedef float2 c32;

__device__ __forceinline__ c32 cmulc(c32 a, c32 b){
    return make_float2(fmaf(a.x, b.x, -(a.y*b.y)), fmaf(a.x, b.y, a.y*b.x));
}
__device__ __forceinline__ c32 caddc(c32 a, c32 b){ return make_float2(a.x+b.x, a.y+b.y); }
__device__ __forceinline__ c32 csubc(c32 a, c32 b){ return make_float2(a.x-b.x, a.y-b.y); }

// In-register DIT FFT of size N (8 or 16), natural-order in/out.
// tw[m] = e^{sign*2*pi*i*m/16}  (sign baked into the table the caller built).
template<int N>
__device__ __forceinline__ void fftN(c32* a, const c32* tw){
    constexpr int LOG = (N == 16) ? 4 : 3;
    c32 b[N];
    #pragma unroll
    for (int i = 0; i < N; ++i){
        int r = 0;
        #pragma unroll
        for (int bb = 0; bb < LOG; ++bb) r = (r << 1) | ((i >> bb) & 1);
        b[i] = a[r];
    }
    #pragma unroll
    for (int len = 2; len <= N; len <<= 1){
        #pragma unroll
        for (int i = 0; i < N; i += len){
            #pragma unroll
            for (int j = 0; j < len/2; ++j){
                c32 t = b[i + j + len/2];
                if (j) t = cmulc(tw[j * (16/len)], t);
                c32 u = b[i + j];
                b[i + j]         = caddc(u, t);
                b[i + j + len/2] = csubc(u, t);
            }
        }
    }
    #pragma unroll
    for (int i = 0; i < N; ++i) a[i] = b[i];
}

// ---------------------------------------------------------------------------
// 1) conv3x3 stride2 SAME + gelu + partial spatial sums (deterministic)
//    grid: (B*T)*8 blocks, 256 thr. Block = 8 output rows of one frame.
//    Thread owns 4 channels (weights in 108 VGPRs, loaded once) x 16 positions.
//    part[(bt*8+rg)*32 + c] = sum over 512 positions of gelu(conv)
// ---------------------------------------------------------------------------
__global__ __launch_bounds__(256) void k_conv(const float* __restrict__ in,
                                              const float* __restrict__ cw,
                                              const float* __restrict__ cb,
                                              float* __restrict__ part)
{
    // xs[c][parity][row][xhalf] : x = 2*xhalf + parity, rows 0..16 of the slab
    __shared__ float xs[3][2][17][68];
    __shared__ float red[4][32];
    const int tid = threadIdx.x;
    const int bt = blockIdx.x >> 3, rg = blockIdx.x & 7;

    // zero even-plane column 64 (x == 128 boundary pad)
    if (tid < 51){ int r = tid / 3, c = tid % 3; xs[c][0][r][64] = 0.0f; }

    // stage slab: input rows r0..r0+16 (17 rows * 384 floats), coalesced
    const int r0 = 16 * rg;
    const float* src = in + (size_t)bt * 49152 + (size_t)r0 * 384;
    for (int i = tid; i < 17 * 384; i += 256){
        int r = i / 384, q = i % 384;
        int x = q / 3, c = q - 3 * x;
        float v = (r0 + r < 128) ? src[i] : 0.0f;
        xs[c][x & 1][r][x >> 1] = v;
    }

    // per-thread weights: 4 channels, 27 taps (float4 = 16B aligned, coalesced)
    const int cg4 = (tid & 7) * 4;      // channel base
    const int pid = tid >> 3;           // 0..31 position column
    float4 w[27];
    #pragma unroll
    for (int q = 0; q < 27; ++q) w[q] = *(const float4*)&cw[q * 32 + cg4];
    const float4 b4 = *(const float4*)&cb[cg4];
    __syncthreads();

    float a0 = 0.f, a1 = 0.f, a2 = 0.f, a3 = 0.f;
    #pragma unroll
    for (int k = 0; k < 16; ++k){
        const int oyl = k >> 1;
        const int ox  = pid + ((k & 1) << 5);
        float iv[27];
        #pragma unroll
        for (int ky = 0; ky < 3; ++ky){
            int row = 2 * oyl + ky;
            #pragma unroll
            for (int ci = 0; ci < 3; ++ci){
                iv[(ky*3 + 0)*3 + ci] = xs[ci][0][row][ox];      // x = 2ox
                iv[(ky*3 + 1)*3 + ci] = xs[ci][1][row][ox];      // x = 2ox+1
                iv[(ky*3 + 2)*3 + ci] = xs[ci][0][row][ox + 1];  // x = 2ox+2
            }
        }
        float s0 = b4.x, s1 = b4.y, s2 = b4.z, s3 = b4.w;
        #pragma unroll
        for (int q = 0; q < 27; ++q){
            s0 = fmaf(iv[q], w[q].x, s0);
            s1 = fmaf(iv[q], w[q].y, s1);
            s2 = fmaf(iv[q], w[q].z, s2);
            s3 = fmaf(iv[q], w[q].w, s3);
        }
        // gelu via fast tanh: tanh(u) = 1 - 2/(1+e^{2u}); exp2/rcp HW ops
        #define GELU_ACC(S, A)                                                      \
        {                                                                           \
            float u_ = 0.7978845608028654f * fmaf(0.044715f * (S), (S)*(S), (S));   \
            float e_ = __builtin_amdgcn_exp2f(2.8853900817779268f * u_);            \
            float t_ = 1.0f - 2.0f * __builtin_amdgcn_rcpf(1.0f + e_);              \
            (A) += 0.5f * (S) * (1.0f + t_);                                        \
        }
        GELU_ACC(s0, a0) GELU_ACC(s1, a1) GELU_ACC(s2, a2) GELU_ACC(s3, a3)
        #undef GELU_ACC
    }

    // reduce over the 8 lane-rows of the wave (lanes cg, cg+8, ..., cg+56)
    const int wave = tid >> 6, lane = tid & 63;
    #pragma unroll
    for (int off = 32; off >= 8; off >>= 1){
        a0 += __shfl_down(a0, off, 64);
        a1 += __shfl_down(a1, off, 64);
        a2 += __shfl_down(a2, off, 64);
        a3 += __shfl_down(a3, off, 64);
    }
    if (lane < 8){
        red[wave][lane*4 + 0] = a0;
        red[wave][lane*4 + 1] = a1;
        red[wave][lane*4 + 2] = a2;
        red[wave][lane*4 + 3] = a3;
    }
    __syncthreads();
    if (tid < 32)
        part[blockIdx.x * 32 + tid] = red[0][tid] + red[1][tid] + red[2][tid] + red[3][tid];
}

// ---------------------------------------------------------------------------
// 2) gates: ctx mean -> alpha/delta (sigmoid), mu/gamma (softplus). 384 thr.
// ---------------------------------------------------------------------------
__global__ __launch_bounds__(64) void k_gates(const float* __restrict__ part,
    const float* __restrict__ wA, const float* __restrict__ bA,
    const float* __restrict__ wD, const float* __restrict__ bD,
    const float* __restrict__ wM, const float* __restrict__ bM,
    const float* __restrict__ wG, const float* __restrict__ bG,
    float* __restrict__ gA, float* __restrict__ gD,
    float* __restrict__ gM, float* __restrict__ gG)
{
    int g = blockIdx.x * 64 + threadIdx.x;
    if (g >= 384) return;
    int bt = g / 3, c = g % 3;
    float sA = bA[c], sD = bD[c], sM = bM[c], sG = bG[c];
    for (int j = 0; j < 32; ++j){
        float cs = 0.f;
        #pragma unroll
        for (int q = 0; q < 8; ++q) cs += part[(bt*8 + q)*32 + j];
        cs *= (1.0f / 4096.0f);
        sA = fmaf(cs, wA[j*3+c], sA);
        sD = fmaf(cs, wD[j*3+c], sD);
        sM = fmaf(cs, wM[j*3+c], sM);
        sG = fmaf(cs, wG[j*3+c], sG);
    }
    gA[g] = 1.0f / (1.0f + expf(-sA));
    gD[g] = 1.0f / (1.0f + expf(-sD));
    gM[g] = fmaxf(sM, 0.f) + log1pf(expf(-fabsf(sM)));
    gG[g] = fmaxf(sG, 0.f) + log1pf(expf(-fabsf(sG)));
}

// ---------------------------------------------------------------------------
// 3) spectral kernels: KE/KI[c][u][v] = rfft2(pad(k, 56)) via direct 256-tap DFT
// ---------------------------------------------------------------------------
__global__ __launch_bounds__(256) void k_spectral(const float* __restrict__ k_exc,
                                                  const float* __restrict__ k_inh,
                                                  float* __restrict__ KEw,
                                                  float* __restrict__ KIw)
{
    __shared__ c32 Wt[128];
    int tid = threadIdx.x;
    if (tid < 128){
        float ang = -0.049087385212340517f * (float)tid;   // -2*pi*t/128
        float s, co; sincosf(ang, &s, &co);
        Wt[tid] = make_float2(co, s);
    }
    __syncthreads();
    int g = blockIdx.x * 256 + tid;
    if (g >= 2 * 24960) return;
    int which = g / 24960, r = g % 24960;
    int c = r / 8320, uv = r % 8320;
    int u_ = uv / 65, v_ = uv % 65;
    const float* kk = which ? k_inh : k_exc;
    float ar = 0.f, ai = 0.f;
    for (int y = 0; y < 16; ++y){
        int pu = u_ * (56 + y);
        #pragma unroll
        for (int x = 0; x < 16; ++x){
            int idx = (pu + v_ * (56 + x)) & 127;
            float kv = kk[(y*16 + x)*3 + c];
            c32 w = Wt[idx];
            ar = fmaf(kv, w.x, ar);
            ai = fmaf(kv, w.y, ai);
        }
    }
    ((float2*)(which ? KIw : KEw))[c*8320 + uv] = make_float2(ar, ai);
}

// ---------------------------------------------------------------------------
// 4) forward rfft2 per (b,t,c) image.  4-step FFT-128 = FFT8 x FFT16.
//    Row pass packs rows (2r, 2r+1) into one complex FFT.  Output
//    U_ws[bt][c][u][v] (v=0..64), complex interleaved.
// ---------------------------------------------------------------------------
__global__ __launch_bounds__(512) void k_fft_fwd(const float* __restrict__ in,
                                                 float* __restrict__ U_ws)
{
    __shared__ c32 A[8320];     // [64][130] for rows, flat [128][65] after unpack
    __shared__ c32 Bf[8320];    // [64][130] for Z rows, flat [128][65] for col out
    __shared__ c32 Wt[128];
    const int tid = threadIdx.x;
    const int img = blockIdx.x;             // bt*3 + c
    const int bt = img / 3, c = img % 3;

    if (tid < 128){
        float ang = -0.049087385212340517f * (float)tid;
        float s, co; sincosf(ang, &s, &co);
        Wt[tid] = make_float2(co, s);
    }
    __syncthreads();
    c32 tw8[8];
    #pragma unroll
    for (int m = 0; m < 8; ++m) tw8[m] = Wt[8*m];

    // pack: A[r*130+x] = in[2r][x] + i*in[2r+1][x]
    const float* src = in + (size_t)bt * 49152 + c;
    for (int p = tid; p < 64*128; p += blockDim.x){
        int r = p >> 7, x = p & 127;
        float re = src[(size_t)((2*r)   * 128 + x) * 3];
        float im = src[(size_t)((2*r+1) * 128 + x) * 3];
        A[r*130 + x] = make_float2(re, im);
    }
    __syncthreads();

    // row stage1: FFT8 over n2 (stride 16), twiddle W[n1*k2], in place
    for (int task = tid; task < 64*16; task += blockDim.x){
        int r = task >> 4, n1 = task & 15;
        c32 v[8];
        #pragma unroll
        for (int n2 = 0; n2 < 8; ++n2) v[n2] = A[r*130 + n1 + 16*n2];
        fftN<8>(v, tw8);
        #pragma unroll
        for (int k2 = 0; k2 < 8; ++k2)
            A[r*130 + n1 + 16*k2] = (k2 == 0) ? v[0] : cmulc(Wt[n1*k2], v[k2]);
    }
    __syncthreads();
    // row stage2: FFT16 over n1 (contiguous), Z[r][k2+8k1] -> Bf
    for (int task = tid; task < 64*8; task += blockDim.x){
        int r = task >> 3, k2 = task & 7;
        c32 v[16];
        #pragma unroll
        for (int n1 = 0; n1 < 16; ++n1) v[n1] = A[r*130 + 16*k2 + n1];
        fftN<16>(v, tw8);
        #pragma unroll
        for (int k1 = 0; k1 < 16; ++k1) Bf[r*130 + k2 + 8*k1] = v[k1];
    }
    __syncthreads();
    // unpack the two packed real rows: A_flat[y*65+v], y = 2r / 2r+1
    for (int task = tid; task < 64*65; task += blockDim.x){
        int r = task / 65, v_ = task % 65;
        c32 zk = Bf[r*130 + v_];
        c32 zn = Bf[r*130 + ((128 - v_) & 127)];
        A[(2*r)  *65 + v_] = make_float2(0.5f*(zk.x + zn.x),  0.5f*(zk.y - zn.y));
        A[(2*r+1)*65 + v_] = make_float2(0.5f*(zk.y + zn.y), -0.5f*(zk.x - zn.x));
    }
    __syncthreads();
    // col stage1: FFT8 over n2 (row stride 16), per column v, in place
    for (int task = tid; task < 16*65; task += blockDim.x){
        int n1 = task / 65, v_ = task % 65;
        c32 v[8];
        #pragma unroll
        for (int n2 = 0; n2 < 8; ++n2) v[n2] = A[(n1 + 16*n2)*65 + v_];
        fftN<8>(v, tw8);
        #pragma unroll
        for (int k2 = 0; k2 < 8; ++k2)
            A[(n1 + 16*k2)*65 + v_] = (k2 == 0) ? v[0] : cmulc(Wt[n1*k2], v[k2]);
    }
    __syncthreads();
    // col stage2: FFT16 over n1, final U[u][v] -> Bf flat
    for (int task = tid; task < 8*65; task += blockDim.x){
        int k2 = task / 65, v_ = task % 65;
        c32 v[16];
        #pragma unroll
        for (int n1 = 0; n1 < 16; ++n1) v[n1] = A[(16*k2 + n1)*65 + v_];
        fftN<16>(v, tw8);
        #pragma unroll
        for (int k1 = 0; k1 < 16; ++k1) Bf[(k2 + 8*k1)*65 + v_] = v[k1];
    }
    __syncthreads();
    float2* dst = ((float2*)U_ws) + (size_t)img * 8320;
    for (int p = tid; p < 8320; p += blockDim.x) dst[p] = Bf[p];
}

// ---------------------------------------------------------------------------
// 5) sequential T-scan (in place over U):  x' = 0.9a*x + (-KI*mu)*y + U,
//    y' = (KE*ga)*x + 0.9d*y ; store y' over U.
// ---------------------------------------------------------------------------
__global__ __launch_bounds__(256) void k_scan(float* __restrict__ U,
    const float* __restrict__ KEw, const float* __restrict__ KIw,
    const float* __restrict__ gA, const float* __restrict__ gD,
    const float* __restrict__ gM, const float* __restrict__ gG)
{
    int g = blockIdx.x * 256 + threadIdx.x;
    if (g >= 4*3*128*65) return;
    int b = g / 24960, r = g % 24960;
    int c = r / 8320, uv = r % 8320;
    float2 ke = ((const float2*)KEw)[c*8320 + uv];
    float2 ki = ((const float2*)KIw)[c*8320 + uv];
    float2* Up = (float2*)U;
    float xr = 0.f, xi = 0.f, yr = 0.f, yi = 0.f;
    for (int t = 0; t < 32; ++t){
        int btc = (b*32 + t)*3 + c;
        float al = 0.9f * gA[btc], de = 0.9f * gD[btc];
        float mu = gM[btc],       ga = gG[btc];
        float axr = -ki.x * mu, axi = -ki.y * mu;
        float ayr =  ke.x * ga, ayi =  ke.y * ga;
        size_t iu = (size_t)btc * 8320 + uv;
        float2 uin = Up[iu];
        float nxr = fmaf(al, xr, fmaf(axr, yr, fmaf(-axi, yi, uin.x)));
        float nxi = fmaf(al, xi, fmaf(axr, yi, fmaf( axi, yr, uin.y)));
        float nyr = fmaf(ayr, xr, fmaf(-ayi, xi, de * yr));
        float nyi = fmaf(ayr, xi, fmaf( ayi, xr, de * yi));
        Up[iu] = make_float2(nyr, nyi);
        xr = nxr; xi = nxi; yr = nyr; yi = nyi;
    }
}

// ---------------------------------------------------------------------------
// 6) inverse: per (b,t,c): column IFFT-128 (65 cols), then real irfft-128 per
//    row via half-size complex IFFT-64 (drops imag of bins 0/64 like numpy).
//    Final scale 1/8192 folds 1/128(col) * 1/64(half-size row).
// ---------------------------------------------------------------------------
__global__ __launch_bounds__(512) void k_fft_inv(const float* __restrict__ Y_ws,
                                                 float* __restrict__ out)
{
    __shared__ c32 A[8320];
    __shared__ c32 Bf[8320];
    __shared__ c32 Wt[128];                 // e^{+2 pi i t/128}
    const int tid = threadIdx.x;
    const int img = blockIdx.x;
    const int bt = img / 3, c = img % 3;

    if (tid < 128){
        float ang = 0.049087385212340517f * (float)tid;
        float s, co; sincosf(ang, &s, &co);
        Wt[tid] = make_float2(co, s);
    }
    __syncthreads();
    c32 tw8[8];
    #pragma unroll
    for (int m = 0; m < 8; ++m) tw8[m] = Wt[8*m];

    const float2* srcv = ((const float2*)Y_ws) + (size_t)img * 8320;
    for (int p = tid; p < 8320; p += blockDim.x) A[p] = srcv[p];
    __syncthreads();

    // col IFFT stage1 (in place, per column v)
    for (int task = tid; task < 16*65; task += blockDim.x){
        int n1 = task / 65, v_ = task % 65;
        c32 v[8];
        #pragma unroll
        for (int n2 = 0; n2 < 8; ++n2) v[n2] = A[(n1 + 16*n2)*65 + v_];
        fftN<8>(v, tw8);
        #pragma unroll
        for (int k2 = 0; k2 < 8; ++k2)
            A[(n1 + 16*k2)*65 + v_] = (k2 == 0) ? v[0] : cmulc(Wt[n1*k2], v[k2]);
    }
    __syncthreads();
    // col IFFT stage2 -> Bf[h][v] = row spectra (unscaled)
    for (int task = tid; task < 8*65; task += blockDim.x){
        int k2 = task / 65, v_ = task % 65;
        c32 v[16];
        #pragma unroll
        for (int n1 = 0; n1 < 16; ++n1) v[n1] = A[(16*k2 + n1)*65 + v_];
        fftN<16>(v, tw8);
        #pragma unroll
        for (int k1 = 0; k1 < 16; ++k1) Bf[(k2 + 8*k1)*65 + v_] = v[k1];
    }
    __syncthreads();
    // E/O prep per row: Z[k] = E[k] + i*O[k], k=0..63 -> A[y*65+k]
    for (int task = tid; task < 128*64; task += blockDim.x){
        int y = task >> 6, k = task & 63;
        c32 Xk = Bf[y*65 + k];
        c32 Xn = Bf[y*65 + 64 - k];
        if (k == 0){ Xk.y = 0.f; Xn.y = 0.f; }     // numpy drops imag of bins 0,64
        float Er = 0.5f*(Xk.x + Xn.x), Ei = 0.5f*(Xk.y - Xn.y);
        c32 d  = make_float2(0.5f*(Xk.x - Xn.x), 0.5f*(Xk.y + Xn.y));
        c32 O  = cmulc(Wt[k], d);                  // e^{+2 pi i k/128} * d
        A[y*65 + k] = make_float2(Er - O.y, Ei + O.x);
    }
    __syncthreads();
    // row IFFT-64 stage1: FFT8 over b at slots a+8b, twiddle e^{+2pi i a c/64}
    for (int task = tid; task < 128*8; task += blockDim.x){
        int y = task >> 3, a = task & 7;
        c32 v[8];
        #pragma unroll
        for (int b2 = 0; b2 < 8; ++b2) v[b2] = A[y*65 + a + 8*b2];
        fftN<8>(v, tw8);
        #pragma unroll
        for (int c2 = 0; c2 < 8; ++c2)
            A[y*65 + a + 8*c2] = (c2 == 0) ? v[0] : cmulc(Wt[2*a*c2], v[c2]);
    }
    __syncthreads();
    // row IFFT-64 stage2: FFT8 over a at slots 8c2+a -> Bf[y*65 + c2+8d]
    for (int task = tid; task < 128*8; task += blockDim.x){
        int y = task >> 3, c2 = task & 7;
        c32 v[8];
        #pragma unroll
        for (int a = 0; a < 8; ++a) v[a] = A[y*65 + 8*c2 + a];
        fftN<8>(v, tw8);
        #pragma unroll
        for (int d = 0; d < 8; ++d) Bf[y*65 + c2 + 8*d] = v[d];
    }
    __syncthreads();
    // emit: x[2m] = Re z, x[2m+1] = Im z, scale 1/8192
    float* dst = out + (size_t)bt * 49152 + c;
    const float sc = 1.0f / 8192.0f;
    for (int p = tid; p < 128*64; p += blockDim.x){
        int y = p >> 6, m = p & 63;
        c32 z = Bf[y*65 + m];
        dst[(size_t)((y << 7) + 2*m    ) * 3] = z.x * sc;
        dst[(size_t)((y << 7) + 2*m + 1) * 3] = z.y * sc;
    }
}

// ---------------------------------------------------------------------------
extern "C" void kernel_launch(void* const* d_in, const int* in_sizes, int n_in,
                              void* d_out, int out_size, void* d_ws, size_t ws_size,
                              hipStream_t stream)
{
    (void)in_sizes; (void)n_in; (void)out_size; (void)ws_size;
    const float* in   = (const float*)d_in[0];
    const float* cw   = (const float*)d_in[1];
    const float* cb   = (const float*)d_in[2];
    const float* wA   = (const float*)d_in[3];
    const float* bA   = (const float*)d_in[4];
    const float* wD   = (const float*)d_in[5];
    const float* bD   = (const float*)d_in[6];
    const float* wM   = (const float*)d_in[7];
    const float* bM   = (const float*)d_in[8];
    const float* wG   = (const float*)d_in[9];
    const float* bG   = (const float*)d_in[10];
    const float* kex  = (const float*)d_in[11];
    const float* kin  = (const float*)d_in[12];
    float* out = (float*)d_out;
    float* ws  = (float*)d_ws;

    float* part = ws;                    // 1024*32            = 32768
    float* gA   = ws + 32768;            // 384
    float* gD   = gA + 384;
    float* gM   = gD + 384;
    float* gG   = gM + 384;              // ends 34304
    float* KEw  = ws + 34304;            // 3*128*65*2         = 49920
    float* KIw  = KEw + 49920;           // ends 134144
    float* U    = ws + 134144;           // 128*3*128*65*2     = 6389760 (in-place scan)

    k_conv    <<<dim3(1024), dim3(256), 0, stream>>>(in, cw, cb, part);
    k_gates   <<<dim3(6),    dim3(64),  0, stream>>>(part, wA, bA, wD, bD, wM, bM, wG, bG,
                                                     gA, gD, gM, gG);
    k_spectral<<<dim3(195),  dim3(256), 0, stream>>>(kex, kin, KEw, KIw);
    k_fft_fwd <<<dim3(384),  dim3(512), 0, stream>>>(in, U);
    k_scan    <<<dim3(390),  dim3(256), 0, stream>>>(U, KEw, KIw, gA, gD, gM, gG);
    k_fft_inv <<<dim3(384),  dim3(512), 0, stream>>>(U, out);
}